// Round 1
// baseline (270.791 us; speedup 1.0000x reference)
//
#include <hip/hip_runtime.h>

// SNN forward: x[B,5] -> L1(5,32) -> spike -> L2(32,32) -> spike
//              -> L3(32,16) -> spike -> L4(16,10) -> spike -> out[B,10]
// spike(h) = (h/TAU >= 1.0) = (h >= 2.0) ? 1.0 : 0.0   (exact: /2 is exact in IEEE)
//
// One thread per row. All weight indices are compile-time constants on
// const __restrict__ kernel-arg pointers -> wave-uniform loads, expected to
// scalarize to s_load (SGPR operand feeding v_fma_f32 directly).

__global__ __launch_bounds__(256) void snn_fwd(
    const float* __restrict__ x,
    const float* __restrict__ W1,   // [32,5]
    const float* __restrict__ W2,   // [32,32]
    const float* __restrict__ W3,   // [16,32]
    const float* __restrict__ W4,   // [10,16]
    float* __restrict__ out,        // [B,10]
    int B)
{
    int row = blockIdx.x * 256 + threadIdx.x;
    bool valid = row < B;
    int r = valid ? row : (B - 1);   // clamp loads, predicate only the store

    const float* xp = x + (long)r * 5;
    float x0 = xp[0], x1 = xp[1], x2 = xp[2], x3 = xp[3], x4 = xp[4];

    // ---- layer 1: 5 -> 32 ----
    float s1[32];
#pragma unroll
    for (int j = 0; j < 32; ++j) {
        const float* w = W1 + j * 5;
        float h = x0 * w[0];
        h += x1 * w[1];
        h += x2 * w[2];
        h += x3 * w[3];
        h += x4 * w[4];
        s1[j] = (h >= 2.0f) ? 1.0f : 0.0f;
    }

    // ---- layer 2: 32 -> 32 ----
    float s2[32];
#pragma unroll
    for (int j = 0; j < 32; ++j) {
        const float* w = W2 + j * 32;
        float h = 0.0f;
#pragma unroll
        for (int i = 0; i < 32; ++i) h += s1[i] * w[i];
        s2[j] = (h >= 2.0f) ? 1.0f : 0.0f;
    }

    // ---- layer 3: 32 -> 16 ----
    float s3[16];
#pragma unroll
    for (int j = 0; j < 16; ++j) {
        const float* w = W3 + j * 32;
        float h = 0.0f;
#pragma unroll
        for (int i = 0; i < 32; ++i) h += s2[i] * w[i];
        s3[j] = (h >= 2.0f) ? 1.0f : 0.0f;
    }

    // ---- layer 4: 16 -> 10 ----
    float o[10];
#pragma unroll
    for (int j = 0; j < 10; ++j) {
        const float* w = W4 + j * 16;
        float h = 0.0f;
#pragma unroll
        for (int i = 0; i < 16; ++i) h += s3[i] * w[i];
        o[j] = (h >= 2.0f) ? 1.0f : 0.0f;
    }

    if (valid) {
        float* op = out + (long)row * 10;
#pragma unroll
        for (int j = 0; j < 10; ++j) op[j] = o[j];
    }
}

extern "C" void kernel_launch(void* const* d_in, const int* in_sizes, int n_in,
                              void* d_out, int out_size, void* d_ws, size_t ws_size,
                              hipStream_t stream) {
    const float* x  = (const float*)d_in[0];
    const float* W1 = (const float*)d_in[1];
    const float* W2 = (const float*)d_in[2];
    const float* W3 = (const float*)d_in[3];
    const float* W4 = (const float*)d_in[4];
    float* out = (float*)d_out;

    int B = in_sizes[0] / 5;
    int grid = (B + 255) / 256;
    snn_fwd<<<grid, 256, 0, stream>>>(x, W1, W2, W3, W4, out, B);
}

// Round 2
// 166.962 us; speedup vs baseline: 1.6219x; 1.6219x over previous
//
#include <hip/hip_runtime.h>

// SNN forward, sparsity-aware two-pass.
//
// spike(h) = (h >= 2.0f) ? 1.0f : 0.0f   (h/TAU >= 1 <=> h >= 2, exact)
//
// Stats: layer-1 spikes fire at ~2.3%/neuron -> ~48% of rows have an all-zero
// spike vector (output exactly 0), and spiking rows have popcount ~1-3.
// Layer-2 activations then almost never reach threshold -> layers 3/4 are a
// rare path. Conditional adds in ascending index order are bit-exact vs the
// reference fma(s_i, w_i, p) chain (s=0 term only perturbs zero-sign).
//
// Kernel A: layer 1, zero-fill output, compact (row,mask) pairs into ws.
// Kernel B: sparse layer 2 from LDS-transposed W2; exact rare path for L3/L4.

#define RPT 8  // rows per thread in kernel A

__global__ __launch_bounds__(256) void snn_l1(
    const float* __restrict__ x,
    const float* __restrict__ W1,
    float* __restrict__ out,
    unsigned* __restrict__ ctr,
    unsigned long long* __restrict__ pairs,
    int B)
{
    __shared__ unsigned scan[256];
    __shared__ unsigned s_base;
    const int t = threadIdx.x;
    const long base = (long)blockIdx.x * (256 * RPT);

    unsigned long long keep[RPT];
    unsigned vmask = 0;

#pragma unroll
    for (int k = 0; k < RPT; ++k) {
        long row = base + (long)k * 256 + t;
        if (row < B) {
            const float* xp = x + row * 5;
            float x0 = xp[0], x1 = xp[1], x2 = xp[2], x3 = xp[3], x4 = xp[4];
            unsigned m = 0u;
#pragma unroll
            for (int j = 0; j < 32; ++j) {
                const float* w = W1 + j * 5;
                float h = x0 * w[0];   // keep exact op order (matched absmax 0)
                h += x1 * w[1];
                h += x2 * w[2];
                h += x3 * w[3];
                h += x4 * w[4];
                if (h >= 2.0f) m |= (1u << j);
            }
            float* op = out + row * 10;
#pragma unroll
            for (int j = 0; j < 10; ++j) op[j] = 0.0f;
            keep[k] = ((unsigned long long)m << 32) | (unsigned)row;
            if (m) vmask |= (1u << k);
        }
    }

    const unsigned n = __popc(vmask);
    scan[t] = n;
    __syncthreads();
    // Hillis-Steele inclusive scan over 256 entries
    for (int off = 1; off < 256; off <<= 1) {
        unsigned v = scan[t];
        unsigned add = (t >= off) ? scan[t - off] : 0u;
        __syncthreads();
        scan[t] = v + add;
        __syncthreads();
    }
    if (t == 255) s_base = atomicAdd(ctr, scan[255]);
    __syncthreads();
    const unsigned excl = scan[t] - n;
    const unsigned gb = s_base;

#pragma unroll
    for (int k = 0; k < RPT; ++k) {
        if ((vmask >> k) & 1u) {
            unsigned pos = gb + excl + __popc(vmask & ((1u << k) - 1u));
            pairs[pos] = keep[k];
        }
    }
}

__global__ __launch_bounds__(256) void snn_rest(
    const float* __restrict__ W2,   // [32,32]
    const float* __restrict__ W3,   // [16,32]
    const float* __restrict__ W4,   // [10,16]
    const unsigned* __restrict__ ctr,
    const unsigned long long* __restrict__ pairs,
    float* __restrict__ out)
{
    __shared__ float w2t[32 * 33];  // transposed, padded: w2t[i*33+j] = W2[j][i]
    const int t = threadIdx.x;
#pragma unroll
    for (int e = t; e < 1024; e += 256) {
        int j = e >> 5, i = e & 31;
        w2t[i * 33 + j] = W2[e];
    }
    __syncthreads();

    const unsigned count = *ctr;
    const long stride = (long)gridDim.x * 256;
    for (long p = (long)blockIdx.x * 256 + t; p < count; p += stride) {
        unsigned long long pr = pairs[p];
        unsigned m = (unsigned)(pr >> 32);
        unsigned row = (unsigned)pr;

        float h[32];
#pragma unroll
        for (int j = 0; j < 32; ++j) h[j] = 0.0f;

        // sparse layer 2: ascending set-bit order == reference accumulation order
        unsigned mm = m;
        while (mm) {
            int i = __ffs(mm) - 1;
            mm &= mm - 1;
            const float* wr = &w2t[i * 33];
#pragma unroll
            for (int j = 0; j < 32; ++j) h[j] += wr[j];
        }

        unsigned m2 = 0u;
#pragma unroll
        for (int j = 0; j < 32; ++j)
            if (h[j] >= 2.0f) m2 |= (1u << j);

        if (m2) {  // rare (O(100) rows total): exact layers 3+4
            unsigned m3 = 0u;
#pragma unroll
            for (int j = 0; j < 16; ++j) {
                float g = 0.0f;
#pragma unroll
                for (int i = 0; i < 32; ++i)
                    if ((m2 >> i) & 1u) g += W3[j * 32 + i];
                if (g >= 2.0f) m3 |= (1u << j);
            }
            float* op = out + (long)row * 10;
#pragma unroll
            for (int j = 0; j < 10; ++j) {
                float g = 0.0f;
#pragma unroll
                for (int i = 0; i < 16; ++i)
                    if ((m3 >> i) & 1u) g += W4[j * 16 + i];
                op[j] = (g >= 2.0f) ? 1.0f : 0.0f;
            }
        }
    }
}

// ---- dense fallback (round-0 kernel) if ws is too small ----
__global__ __launch_bounds__(256) void snn_fwd_dense(
    const float* __restrict__ x, const float* __restrict__ W1,
    const float* __restrict__ W2, const float* __restrict__ W3,
    const float* __restrict__ W4, float* __restrict__ out, int B)
{
    int row = blockIdx.x * 256 + threadIdx.x;
    bool valid = row < B;
    int r = valid ? row : (B - 1);
    const float* xp = x + (long)r * 5;
    float x0 = xp[0], x1 = xp[1], x2 = xp[2], x3 = xp[3], x4 = xp[4];
    float s1[32];
#pragma unroll
    for (int j = 0; j < 32; ++j) {
        const float* w = W1 + j * 5;
        float h = x0 * w[0];
        h += x1 * w[1]; h += x2 * w[2]; h += x3 * w[3]; h += x4 * w[4];
        s1[j] = (h >= 2.0f) ? 1.0f : 0.0f;
    }
    float s2[32];
#pragma unroll
    for (int j = 0; j < 32; ++j) {
        const float* w = W2 + j * 32;
        float h = 0.0f;
#pragma unroll
        for (int i = 0; i < 32; ++i) h += s1[i] * w[i];
        s2[j] = (h >= 2.0f) ? 1.0f : 0.0f;
    }
    float s3[16];
#pragma unroll
    for (int j = 0; j < 16; ++j) {
        const float* w = W3 + j * 32;
        float h = 0.0f;
#pragma unroll
        for (int i = 0; i < 32; ++i) h += s2[i] * w[i];
        s3[j] = (h >= 2.0f) ? 1.0f : 0.0f;
    }
    float o[10];
#pragma unroll
    for (int j = 0; j < 10; ++j) {
        const float* w = W4 + j * 16;
        float h = 0.0f;
#pragma unroll
        for (int i = 0; i < 16; ++i) h += s3[i] * w[i];
        o[j] = (h >= 2.0f) ? 1.0f : 0.0f;
    }
    if (valid) {
        float* op = out + (long)row * 10;
#pragma unroll
        for (int j = 0; j < 10; ++j) op[j] = o[j];
    }
}

extern "C" void kernel_launch(void* const* d_in, const int* in_sizes, int n_in,
                              void* d_out, int out_size, void* d_ws, size_t ws_size,
                              hipStream_t stream) {
    const float* x  = (const float*)d_in[0];
    const float* W1 = (const float*)d_in[1];
    const float* W2 = (const float*)d_in[2];
    const float* W3 = (const float*)d_in[3];
    const float* W4 = (const float*)d_in[4];
    float* out = (float*)d_out;

    int B = in_sizes[0] / 5;
    size_t need = 16 + (size_t)B * 8;

    if (ws_size >= need) {
        unsigned* ctr = (unsigned*)d_ws;
        unsigned long long* pairs = (unsigned long long*)((char*)d_ws + 16);
        hipMemsetAsync(d_ws, 0, 16, stream);  // ws is re-poisoned 0xAA each call
        int gridA = (B + 256 * RPT - 1) / (256 * RPT);
        snn_l1<<<gridA, 256, 0, stream>>>(x, W1, out, ctr, pairs, B);
        snn_rest<<<1024, 256, 0, stream>>>(W2, W3, W4, ctr, pairs, out);
    } else {
        int grid = (B + 255) / 256;
        snn_fwd_dense<<<grid, 256, 0, stream>>>(x, W1, W2, W3, W4, out, B);
    }
}

// Round 3
// 154.762 us; speedup vs baseline: 1.7497x; 1.0788x over previous
//
#include <hip/hip_runtime.h>

// SNN forward, sparsity-aware two-pass, coalesced.
//
// spike(h) = (h >= 2.0f)   (h/TAU >= 1 <=> h >= 2, exact in IEEE)
//
// ~48% of rows have an all-zero layer-1 spike vector (output exactly 0);
// spiking rows have popcount ~1-3 and layer-2 almost never fires -> layers
// 3/4 are a rare exact path. Conditional adds in ascending index order are
// bit-exact vs the reference fma(s_i,w_i,p) chain (absmax 0.0 verified R1/R2).
//
// R3: kernel A fully coalesced — x staged via LDS float4, out zero-filled
// with float4 over the block's contiguous 80KB range. Kernel B: W2^T padded
// to 36 floats/row for ds_read_b128 vectorization.

#define RPB 2048   // rows per block in kernel A (256 thr x 8 chunks)

__global__ __launch_bounds__(256) void snn_l1(
    const float* __restrict__ x,
    const float* __restrict__ W1,
    float* __restrict__ out,
    unsigned* __restrict__ ctr,
    unsigned long long* __restrict__ pairs,
    int B)
{
    __shared__ float xs[RPB * 5];     // 40 KB staged x
    __shared__ unsigned scan[256];
    __shared__ unsigned s_base;
    const int t = threadIdx.x;
    const long base = (long)blockIdx.x * RPB;
    const int nrows = (int)min((long)RPB, (long)B - base);

    // ---- coalesced x stage + out zero-fill ----
    if (nrows == RPB) {
        const float4* xg = (const float4*)(x + base * 5);
        float4* xs4 = (float4*)xs;
#pragma unroll
        for (int e = 0; e < 10; ++e)           // 2560 float4s
            xs4[e * 256 + t] = xg[e * 256 + t];
        float4* og = (float4*)(out + base * 10);
        const float4 z = make_float4(0.f, 0.f, 0.f, 0.f);
#pragma unroll
        for (int e = 0; e < 20; ++e)           // 5120 float4s
            og[e * 256 + t] = z;
    } else {
        for (int e = t; e < nrows * 5; e += 256) xs[e] = x[base * 5 + e];
        for (int e = t; e < nrows * 10; e += 256) out[base * 10 + e] = 0.0f;
    }
    __syncthreads();

    // ---- layer 1 masks (weights are wave-uniform -> scalarized loads) ----
    unsigned long long keep[8];
    unsigned vmask = 0;
#pragma unroll
    for (int c = 0; c < 8; ++c) {
        int lr = c * 256 + t;
        if (lr < nrows) {
            const float* xp = &xs[lr * 5];
            float x0 = xp[0], x1 = xp[1], x2 = xp[2], x3 = xp[3], x4 = xp[4];
            unsigned m = 0u;
#pragma unroll
            for (int j = 0; j < 32; ++j) {
                const float* w = W1 + j * 5;
                float h = x0 * w[0];   // exact reference op order
                h += x1 * w[1];
                h += x2 * w[2];
                h += x3 * w[3];
                h += x4 * w[4];
                if (h >= 2.0f) m |= (1u << j);
            }
            keep[c] = ((unsigned long long)m << 32) | (unsigned)(base + lr);
            if (m) vmask |= (1u << c);
        }
    }

    // ---- block compaction of spiking rows ----
    const unsigned n = __popc(vmask);
    scan[t] = n;
    __syncthreads();
    for (int off = 1; off < 256; off <<= 1) {
        unsigned v = scan[t];
        unsigned add = (t >= off) ? scan[t - off] : 0u;
        __syncthreads();
        scan[t] = v + add;
        __syncthreads();
    }
    if (t == 255) s_base = atomicAdd(ctr, scan[255]);
    __syncthreads();
    const unsigned excl = scan[t] - n;
    const unsigned gb = s_base;
#pragma unroll
    for (int c = 0; c < 8; ++c) {
        if ((vmask >> c) & 1u) {
            unsigned pos = gb + excl + __popc(vmask & ((1u << c) - 1u));
            pairs[pos] = keep[c];
        }
    }
}

__global__ __launch_bounds__(256) void snn_rest(
    const float* __restrict__ W2,   // [32,32]
    const float* __restrict__ W3,   // [16,32]
    const float* __restrict__ W4,   // [10,16]
    const unsigned* __restrict__ ctr,
    const unsigned long long* __restrict__ pairs,
    float* __restrict__ out)
{
    __shared__ float w2t[32 * 36];  // transposed, 144B rows (16B-aligned)
    const int t = threadIdx.x;
#pragma unroll
    for (int e = t; e < 1024; e += 256) {
        int j = e >> 5, i = e & 31;
        w2t[i * 36 + j] = W2[e];
    }
    __syncthreads();

    const unsigned count = *ctr;
    const long stride = (long)gridDim.x * 256;
    for (long p = (long)blockIdx.x * 256 + t; p < count; p += stride) {
        unsigned long long pr = pairs[p];
        unsigned m = (unsigned)(pr >> 32);
        unsigned row = (unsigned)pr;

        float h[32];
#pragma unroll
        for (int j = 0; j < 32; ++j) h[j] = 0.0f;

        // sparse layer 2: ascending set-bit order == reference order
        unsigned mm = m;
        while (mm) {
            int i = __ffs(mm) - 1;
            mm &= mm - 1;
            const float* wr = &w2t[i * 36];
#pragma unroll
            for (int j = 0; j < 32; ++j) h[j] += wr[j];
        }

        unsigned m2 = 0u;
#pragma unroll
        for (int j = 0; j < 32; ++j)
            if (h[j] >= 2.0f) m2 |= (1u << j);

        if (m2) {  // rare (O(100) rows): exact layers 3+4
            unsigned m3 = 0u;
#pragma unroll
            for (int j = 0; j < 16; ++j) {
                float g = 0.0f;
#pragma unroll
                for (int i = 0; i < 32; ++i)
                    if ((m2 >> i) & 1u) g += W3[j * 32 + i];
                if (g >= 2.0f) m3 |= (1u << j);
            }
            float* op = out + (long)row * 10;
#pragma unroll
            for (int j = 0; j < 10; ++j) {
                float g = 0.0f;
#pragma unroll
                for (int i = 0; i < 16; ++i)
                    if ((m3 >> i) & 1u) g += W4[j * 16 + i];
                op[j] = (g >= 2.0f) ? 1.0f : 0.0f;
            }
        }
    }
}

// ---- dense fallback if ws is too small ----
__global__ __launch_bounds__(256) void snn_fwd_dense(
    const float* __restrict__ x, const float* __restrict__ W1,
    const float* __restrict__ W2, const float* __restrict__ W3,
    const float* __restrict__ W4, float* __restrict__ out, int B)
{
    int row = blockIdx.x * 256 + threadIdx.x;
    bool valid = row < B;
    int r = valid ? row : (B - 1);
    const float* xp = x + (long)r * 5;
    float x0 = xp[0], x1 = xp[1], x2 = xp[2], x3 = xp[3], x4 = xp[4];
    float s1[32];
#pragma unroll
    for (int j = 0; j < 32; ++j) {
        const float* w = W1 + j * 5;
        float h = x0 * w[0];
        h += x1 * w[1]; h += x2 * w[2]; h += x3 * w[3]; h += x4 * w[4];
        s1[j] = (h >= 2.0f) ? 1.0f : 0.0f;
    }
    float s2[32];
#pragma unroll
    for (int j = 0; j < 32; ++j) {
        const float* w = W2 + j * 32;
        float h = 0.0f;
#pragma unroll
        for (int i = 0; i < 32; ++i) h += s1[i] * w[i];
        s2[j] = (h >= 2.0f) ? 1.0f : 0.0f;
    }
    float s3[16];
#pragma unroll
    for (int j = 0; j < 16; ++j) {
        const float* w = W3 + j * 32;
        float h = 0.0f;
#pragma unroll
        for (int i = 0; i < 32; ++i) h += s2[i] * w[i];
        s3[j] = (h >= 2.0f) ? 1.0f : 0.0f;
    }
    float o[10];
#pragma unroll
    for (int j = 0; j < 10; ++j) {
        const float* w = W4 + j * 16;
        float h = 0.0f;
#pragma unroll
        for (int i = 0; i < 16; ++i) h += s3[i] * w[i];
        o[j] = (h >= 2.0f) ? 1.0f : 0.0f;
    }
    if (valid) {
        float* op = out + (long)row * 10;
#pragma unroll
        for (int j = 0; j < 10; ++j) op[j] = o[j];
    }
}

extern "C" void kernel_launch(void* const* d_in, const int* in_sizes, int n_in,
                              void* d_out, int out_size, void* d_ws, size_t ws_size,
                              hipStream_t stream) {
    const float* x  = (const float*)d_in[0];
    const float* W1 = (const float*)d_in[1];
    const float* W2 = (const float*)d_in[2];
    const float* W3 = (const float*)d_in[3];
    const float* W4 = (const float*)d_in[4];
    float* out = (float*)d_out;

    int B = in_sizes[0] / 5;
    size_t need = 16 + (size_t)B * 8;

    if (ws_size >= need) {
        unsigned* ctr = (unsigned*)d_ws;
        unsigned long long* pairs = (unsigned long long*)((char*)d_ws + 16);
        hipMemsetAsync(d_ws, 0, 16, stream);
        int gridA = (B + RPB - 1) / RPB;
        snn_l1<<<gridA, 256, 0, stream>>>(x, W1, out, ctr, pairs, B);
        snn_rest<<<1024, 256, 0, stream>>>(W2, W3, W4, ctr, pairs, out);
    } else {
        int grid = (B + 255) / 256;
        snn_fwd_dense<<<grid, 256, 0, stream>>>(x, W1, W2, W3, W4, out, B);
    }
}

// Round 5
// 141.179 us; speedup vs baseline: 1.9181x; 1.0962x over previous
//
#include <hip/hip_runtime.h>

// SNN forward, fully fused single-pass.
//
// spike(h) = (h >= 2.0f)   (h/TAU >= 1 <=> h >= 2, exact in IEEE)
//
// ~48% of rows: layer-1 spike vector all-zero -> output exactly 0.
// Spiking rows: popcount(m1) ~1-3; layer-2 then almost never fires, so
// layers 3/4 are a rare (O(100) rows) exact path. Conditional adds in
// ascending index order are bit-exact vs the reference fma chain
// (absmax 0.0 verified R1-R3).
//
// R4: one kernel. Per block of 512 rows: coalesced float4 x-stage into LDS,
// inline L1 mask + sparse L2 (LDS W2^T, 36-float padded rows for
// ds_read_b128), rare L3/L4 from global, outputs staged in LDS (union with
// x-stage) and flushed as coalesced nontemporal 16B stores. No ws, no
// atomics, no inter-block machinery. ~25KB LDS -> 6 blocks/CU.
//
// Note: __builtin_nontemporal_store needs a NATIVE vector type, not HIP's
// float4 class -> use ext_vector_type(4).

typedef float v4f __attribute__((ext_vector_type(4)));

#define RPB 512   // rows per block (256 threads x 2 rows)

__global__ __launch_bounds__(256) void snn_fused(
    const float* __restrict__ x,
    const float* __restrict__ W1,   // [32,5]
    const float* __restrict__ W2,   // [32,32]
    const float* __restrict__ W3,   // [16,32]
    const float* __restrict__ W4,   // [10,16]
    float* __restrict__ out,        // [B,10]
    int B)
{
    __shared__ float buf[RPB * 10];   // 20KB union: x-stage (RPB*5) / out (RPB*10)
    __shared__ float w2t[32 * 36];    // W2 transposed, 144B rows (16B-aligned)

    const int t = threadIdx.x;
    const long base = (long)blockIdx.x * RPB;
    const int nrows = (int)min((long)RPB, (long)B - base);

    // ---- stage W2^T ----
#pragma unroll
    for (int e = t; e < 1024; e += 256) {
        int j = e >> 5, i = e & 31;
        w2t[i * 36 + j] = W2[e];
    }

    // ---- coalesced x stage: RPB*5 = 2560 floats = 640 v4f ----
    if (nrows == RPB) {
        const v4f* xg = (const v4f*)(x + base * 5);
        v4f* b4 = (v4f*)buf;
#pragma unroll
        for (int e = 0; e < 3; ++e) {
            int idx = e * 256 + t;
            if (idx < (RPB * 5) / 4) b4[idx] = xg[idx];
        }
    } else {
        for (int e = t; e < nrows * 5; e += 256) buf[e] = x[base * 5 + e];
    }
    __syncthreads();

    // ---- pull own rows' x into registers (buf gets overwritten below) ----
    float xr[2][5];
#pragma unroll
    for (int c = 0; c < 2; ++c) {
        int lr = c * 256 + t;
        if (lr < nrows) {
#pragma unroll
            for (int k = 0; k < 5; ++k) xr[c][k] = buf[lr * 5 + k];
        }
    }
    __syncthreads();

    // ---- per-row compute, write o[10] into LDS out region ----
#pragma unroll
    for (int c = 0; c < 2; ++c) {
        int lr = c * 256 + t;
        if (lr >= nrows) continue;

        // layer 1 mask (W1 wave-uniform -> scalar loads)
        unsigned m = 0u;
#pragma unroll
        for (int j = 0; j < 32; ++j) {
            const float* w = W1 + j * 5;
            float h = xr[c][0] * w[0];   // exact reference op order
            h += xr[c][1] * w[1];
            h += xr[c][2] * w[2];
            h += xr[c][3] * w[3];
            h += xr[c][4] * w[4];
            if (h >= 2.0f) m |= (1u << j);
        }

        float o[10];
#pragma unroll
        for (int j = 0; j < 10; ++j) o[j] = 0.0f;

        if (m) {
            // sparse layer 2: ascending set-bit order == reference order
            float h[32];
#pragma unroll
            for (int j = 0; j < 32; ++j) h[j] = 0.0f;
            unsigned mm = m;
            while (mm) {
                int i = __ffs(mm) - 1;
                mm &= mm - 1;
                const float* wr = &w2t[i * 36];
#pragma unroll
                for (int j = 0; j < 32; ++j) h[j] += wr[j];
            }
            unsigned m2 = 0u;
#pragma unroll
            for (int j = 0; j < 32; ++j)
                if (h[j] >= 2.0f) m2 |= (1u << j);

            if (m2) {  // rare (O(100) rows total): exact layers 3+4
                unsigned m3 = 0u;
#pragma unroll
                for (int j = 0; j < 16; ++j) {
                    float g = 0.0f;
#pragma unroll
                    for (int i = 0; i < 32; ++i)
                        if ((m2 >> i) & 1u) g += W3[j * 32 + i];
                    if (g >= 2.0f) m3 |= (1u << j);
                }
#pragma unroll
                for (int j = 0; j < 10; ++j) {
                    float g = 0.0f;
#pragma unroll
                    for (int i = 0; i < 16; ++i)
                        if ((m3 >> i) & 1u) g += W4[j * 16 + i];
                    o[j] = (g >= 2.0f) ? 1.0f : 0.0f;
                }
            }
        }

#pragma unroll
        for (int j = 0; j < 10; ++j) buf[lr * 10 + j] = o[j];
    }
    __syncthreads();

    // ---- coalesced nontemporal flush: RPB*10 = 5120 floats = 1280 v4f ----
    if (nrows == RPB) {
        v4f* og = (v4f*)(out + base * 10);
        const v4f* b4 = (const v4f*)buf;
#pragma unroll
        for (int e = 0; e < 5; ++e) {
            int idx = e * 256 + t;
            __builtin_nontemporal_store(b4[idx], &og[idx]);
        }
    } else {
        for (int e = t; e < nrows * 10; e += 256) out[base * 10 + e] = buf[e];
    }
}

extern "C" void kernel_launch(void* const* d_in, const int* in_sizes, int n_in,
                              void* d_out, int out_size, void* d_ws, size_t ws_size,
                              hipStream_t stream) {
    const float* x  = (const float*)d_in[0];
    const float* W1 = (const float*)d_in[1];
    const float* W2 = (const float*)d_in[2];
    const float* W3 = (const float*)d_in[3];
    const float* W4 = (const float*)d_in[4];
    float* out = (float*)d_out;

    int B = in_sizes[0] / 5;
    int grid = (B + RPB - 1) / RPB;
    snn_fused<<<grid, 256, 0, stream>>>(x, W1, W2, W3, W4, out, B);
}